// Round 1
// baseline (383.828 us; speedup 1.0000x reference)
//
#include <hip/hip_runtime.h>

#define B_ 128
#define T_ 256
#define H_ 768
#define K_ 64
#define BT_ (B_ * T_)

// ---------------------------------------------------------------------------
// Kernel A: emissions[bt][k] = hidden[bt][:] @ W[:][k] + b[k]   (fp32)
// 256 blocks x 256 threads; block tile = 128 rows x 64 cols; BK = 64.
// Microtile per thread: 8 rows x 4 cols.
// ---------------------------------------------------------------------------
__global__ __launch_bounds__(256) void gemm_emis(const float* __restrict__ hidden,
                                                 const float* __restrict__ W,
                                                 const float* __restrict__ bias,
                                                 float* __restrict__ emis) {
    // At padded to 65 floats/row: inner-loop reads At[row][h] land on 4 distinct
    // banks across the wave's 4 row-groups (8*65 % 32 = 8*ty stride).
    __shared__ float At[128 * 65];
    __shared__ float Wt[64 * 64];

    const int tid = threadIdx.x;
    const int tx = tid & 15;   // col group: 4 cols
    const int ty = tid >> 4;   // row group: 8 rows
    const int rowbase = blockIdx.x * 128;

    float acc[8][4];
#pragma unroll
    for (int r = 0; r < 8; ++r)
#pragma unroll
        for (int c = 0; c < 4; ++c) acc[r][c] = 0.f;

    for (int hb = 0; hb < H_; hb += 64) {
        // stage A: 128 rows x 64 h (float4 along h, coalesced)
#pragma unroll
        for (int k = 0; k < 8; ++k) {
            int f = tid + k * 256;
            int row = f >> 4;
            int hq = f & 15;
            float4 v = *(const float4*)&hidden[(size_t)(rowbase + row) * H_ + hb + hq * 4];
            At[row * 65 + hq * 4 + 0] = v.x;
            At[row * 65 + hq * 4 + 1] = v.y;
            At[row * 65 + hq * 4 + 2] = v.z;
            At[row * 65 + hq * 4 + 3] = v.w;
        }
        // stage W: 64 h x 64 cols (coalesced float4)
#pragma unroll
        for (int k = 0; k < 4; ++k) {
            int f = tid + k * 256;
            int wr = f >> 4;
            int wc = f & 15;
            float4 v = *(const float4*)&W[(size_t)(hb + wr) * K_ + wc * 4];
            *(float4*)&Wt[wr * 64 + wc * 4] = v;
        }
        __syncthreads();
#pragma unroll 8
        for (int h = 0; h < 64; ++h) {
            float4 wv = *(float4*)&Wt[h * 64 + tx * 4];
#pragma unroll
            for (int r = 0; r < 8; ++r) {
                float av = At[(ty * 8 + r) * 65 + h];
                acc[r][0] += av * wv.x;
                acc[r][1] += av * wv.y;
                acc[r][2] += av * wv.z;
                acc[r][3] += av * wv.w;
            }
        }
        __syncthreads();
    }

    float4 bv = *(const float4*)&bias[tx * 4];
#pragma unroll
    for (int r = 0; r < 8; ++r) {
        float4 o;
        o.x = acc[r][0] + bv.x;
        o.y = acc[r][1] + bv.y;
        o.z = acc[r][2] + bv.z;
        o.w = acc[r][3] + bv.w;
        *(float4*)&emis[(size_t)(rowbase + ty * 8 + r) * K_ + tx * 4] = o;
    }
}

// ---------------------------------------------------------------------------
// Kernel B: CRF. One wave (64 lanes = 64 states) per batch per recurrence.
// blocks 0..127  : forward log-norm + sequence score -> out[32768 + b]
// blocks 128..255: Viterbi + backtrack -> out[b*256 .. b*256+255] (as float)
// ---------------------------------------------------------------------------
__global__ __launch_bounds__(64) void crf_kernel(const float* __restrict__ emis,
                                                 const int* __restrict__ masks,
                                                 const int* __restrict__ target,
                                                 const float* __restrict__ trans,
                                                 float* __restrict__ out) {
    __shared__ unsigned char bpb[255 * 64];  // backpointers (Viterbi blocks)
    __shared__ float fbuf[64];               // alpha / v broadcast buffer
    __shared__ int pathb[256];               // decoded path (Viterbi blocks)

    const int lane = threadIdx.x;
    const int bid = blockIdx.x;
    const int b = (bid < B_) ? bid : bid - B_;

    // seq_len = sum(masks[b])
    int sl = 0;
#pragma unroll
    for (int k = 0; k < 4; ++k) sl += masks[b * T_ + lane + k * 64];
#pragma unroll
    for (int m = 32; m; m >>= 1) sl += __shfl_xor(sl, m, 64);
    const int seq_len = sl;

    const float* eb = emis + (size_t)b * (T_ * K_);

    if (bid < B_) {
        // ---------------- forward (log-norm) + sequence score ----------------
        float Ecol[64];  // exp(trans[:, lane]) in registers
#pragma unroll
        for (int i = 0; i < 64; ++i) Ecol[i] = __expf(trans[i * K_ + lane]);

        float a = eb[lane];            // alpha_0
        float e_t = eb[K_ + lane];     // emis[t=1]
        for (int t = 1; t < T_; ++t) {
            float e_next = (t < T_ - 1) ? eb[(t + 1) * K_ + lane] : 0.f;
            // stabilization shift: lane0's alpha (spread across lanes is <~5)
            float m0 = __shfl(a, 0, 64);
            float p = __expf(a - m0);
            fbuf[lane] = p;  // single wave: DS pipe is in-order, no barrier
            float s0 = 0.f, s1 = 0.f, s2 = 0.f, s3 = 0.f;
#pragma unroll
            for (int i = 0; i < 16; ++i) {
                float4 p4 = *(float4*)&fbuf[i * 4];
                s0 += p4.x * Ecol[i * 4 + 0];
                s1 += p4.y * Ecol[i * 4 + 1];
                s2 += p4.z * Ecol[i * 4 + 2];
                s3 += p4.w * Ecol[i * 4 + 3];
            }
            float na = m0 + __logf((s0 + s1) + (s2 + s3)) + e_t;
            if (t < seq_len) a = na;
            e_t = e_next;
        }
        // log_norm = logsumexp over lanes of a
        float mm = a;
#pragma unroll
        for (int m = 32; m; m >>= 1) mm = fmaxf(mm, __shfl_xor(mm, m, 64));
        float ex = __expf(a - mm);
#pragma unroll
        for (int m = 32; m; m >>= 1) ex += __shfl_xor(ex, m, 64);
        float log_norm = mm + __logf(ex);

        // sequence score
        float sc = 0.f;
#pragma unroll
        for (int k = 0; k < 4; ++k) {
            int t = lane + k * 64;
            if (t < seq_len) {
                int tg = target[b * T_ + t];
                sc += eb[t * K_ + tg];
                if (t >= 1) {
                    int tp = target[b * T_ + t - 1];
                    sc += trans[tp * K_ + tg];
                }
            }
        }
#pragma unroll
        for (int m = 32; m; m >>= 1) sc += __shfl_xor(sc, m, 64);
        if (lane == 0) out[BT_ + b] = sc - log_norm;
    } else {
        // ---------------- Viterbi + backtrack ----------------
        float Tcol[64];  // trans[:, lane] in registers
#pragma unroll
        for (int i = 0; i < 64; ++i) Tcol[i] = trans[i * K_ + lane];

        float v = eb[lane];
        float e_t = eb[K_ + lane];
        for (int t = 1; t < T_; ++t) {
            float e_next = (t < T_ - 1) ? eb[(t + 1) * K_ + lane] : 0.f;
            fbuf[lane] = v;  // single wave, in-order DS
            float best = -3.4e38f;
            int bi = 0;
#pragma unroll
            for (int i = 0; i < 16; ++i) {
                float4 v4 = *(float4*)&fbuf[i * 4];
                float s;
                s = v4.x + Tcol[i * 4 + 0]; if (s > best) { best = s; bi = i * 4 + 0; }
                s = v4.y + Tcol[i * 4 + 1]; if (s > best) { best = s; bi = i * 4 + 1; }
                s = v4.z + Tcol[i * 4 + 2]; if (s > best) { best = s; bi = i * 4 + 2; }
                s = v4.w + Tcol[i * 4 + 3]; if (s > best) { best = s; bi = i * 4 + 3; }
            }
            int bp;
            if (t < seq_len) { v = best + e_t; bp = bi; }
            else             { bp = lane; }   // identity bp when masked (ref semantics)
            bpb[(t - 1) * 64 + lane] = (unsigned char)bp;
            e_t = e_next;
        }
        // last tag = argmax over lanes of v, first index on ties (np.argmax)
        float bv = v;
        int bidx = lane;
#pragma unroll
        for (int m = 32; m; m >>= 1) {
            float ov = __shfl_xor(bv, m, 64);
            int oi = __shfl_xor(bidx, m, 64);
            if (ov > bv || (ov == bv && oi < bidx)) { bv = ov; bidx = oi; }
        }
        int tag = bidx;  // identical on all lanes

        // backtrack (all lanes redundantly; broadcast LDS reads)
        pathb[255] = tag;
        for (int t = T_ - 1; t >= 1; --t) {
            tag = bpb[(t - 1) * 64 + tag];
            pathb[t - 1] = tag;
        }
        // write path (mask invalid -> 0), decode values as exact floats
#pragma unroll
        for (int k = 0; k < 4; ++k) {
            int t = lane + k * 64;
            out[b * T_ + t] = (t < seq_len) ? (float)pathb[t] : 0.f;
        }
    }
}

// ---------------------------------------------------------------------------
extern "C" void kernel_launch(void* const* d_in, const int* in_sizes, int n_in,
                              void* d_out, int out_size, void* d_ws, size_t ws_size,
                              hipStream_t stream) {
    const float* hidden = (const float*)d_in[0];   // [B,T,H] fp32
    const int* masks    = (const int*)d_in[1];     // [B,T] int32
    const int* target   = (const int*)d_in[2];     // [B,T] int32
    const float* W      = (const float*)d_in[3];   // [H,K] fp32
    const float* bias   = (const float*)d_in[4];   // [K] fp32
    const float* trans  = (const float*)d_in[5];   // [K,K] fp32
    float* out = (float*)d_out;                    // [B*T] path + [B] ll, fp32
    float* emis = (float*)d_ws;                    // [B*T, K] fp32 scratch

    gemm_emis<<<dim3(BT_ / 128), dim3(256), 0, stream>>>(hidden, W, bias, emis);
    crf_kernel<<<dim3(2 * B_), dim3(64), 0, stream>>>(emis, masks, target, trans, out);
}